// Round 3
// baseline (48726.343 us; speedup 1.0000x reference)
//
#include <hip/hip_runtime.h>
#include <math.h>

// Problem constants
#define BB 64      // batch
#define SS 512     // seq
#define EE 256     // embed
#define HH 512     // hidden

// ---------------------------------------------------------------------------
// Stages:
//   1. transpose W_hh0, W_hh1 -> WT (rec kernel weight loads coalesce)
//   2. xp0 = emb[x] @ W_ih0^T + b_ih0 + b_hh0      (tiled GEMM w/ gather)
//   3. layer-0 recurrence (32 blocks x 2 batches)  -> out0
//   4. xp1 = out0 @ W_ih1^T + b_ih1 + b_hh1        (tiled GEMM)
//   5. layer-1 recurrence -> pooled
//   6. out = pooled @ W_out^T + b_out
//
// Round-3 rec_kernel: round-1 structure (plain __syncthreads -- round 2's
// asm barriers + __launch_bounds__(1024,4) caused a 64-VGPR cap -> wb[]
// spilled to scratch -> 96MB spill writes + 2GB HBM fetch + 6x slowdown).
// Now: __launch_bounds__(1024,1) (128-VGPR budget under either arg
// semantics) + 2-chunk register prefetch pipeline over the step-invariant
// weight stream.
// ---------------------------------------------------------------------------

// W transpose: WT[j][i] = W[i][j], 512x512
__global__ void transpose512(const float* __restrict__ in, float* __restrict__ out) {
  __shared__ float tile[32][33];
  int bx = blockIdx.x * 32, by = blockIdx.y * 32;
  int x = threadIdx.x, y0 = threadIdx.y;  // block (32,8)
  for (int dy = 0; dy < 32; dy += 8)
    tile[y0 + dy][x] = in[(size_t)(by + y0 + dy) * HH + bx + x];
  __syncthreads();
  for (int dy = 0; dy < 32; dy += 8)
    out[(size_t)(bx + y0 + dy) * HH + by + x] = tile[x][y0 + dy];
}

// Tiled GEMM: C[m][n] = sum_k A[m][k] * Wn[n][k] + bias1[n] + bias2[n]
template <int K, bool GATHER>
__global__ __launch_bounds__(256) void xp_gemm(
    const float* __restrict__ Asrc, const int* __restrict__ xidx,
    const float* __restrict__ emb, const float* __restrict__ Wn,
    const float* __restrict__ bias1, const float* __restrict__ bias2,
    float* __restrict__ C) {
  const int tid = threadIdx.x;
  const int m0 = blockIdx.x * 64;
  const int n0 = blockIdx.y * 64;
  __shared__ alignas(16) float As[32][68];
  __shared__ alignas(16) float Bs[32][68];
  __shared__ int xs[64];
  if (GATHER) {
    if (tid < 64) xs[tid] = xidx[m0 + tid];
    __syncthreads();
  }
  float acc[4][4] = {};
  const int ty = tid >> 4, tx = tid & 15;
  const int row = tid >> 2;          // 0..63
  const int kc = (tid & 3) * 8;      // 0,8,16,24

  for (int k0 = 0; k0 < K; k0 += 32) {
    const float* ap;
    if (GATHER) ap = emb + (size_t)xs[row] * EE + (k0 + kc);
    else        ap = Asrc + (size_t)(m0 + row) * K + (k0 + kc);
    float4 av0 = *(const float4*)ap;
    float4 av1 = *(const float4*)(ap + 4);
    const float* bp = Wn + (size_t)(n0 + row) * K + (k0 + kc);
    float4 bv0 = *(const float4*)bp;
    float4 bv1 = *(const float4*)(bp + 4);
    __syncthreads();
    As[kc + 0][row] = av0.x; As[kc + 1][row] = av0.y;
    As[kc + 2][row] = av0.z; As[kc + 3][row] = av0.w;
    As[kc + 4][row] = av1.x; As[kc + 5][row] = av1.y;
    As[kc + 6][row] = av1.z; As[kc + 7][row] = av1.w;
    Bs[kc + 0][row] = bv0.x; Bs[kc + 1][row] = bv0.y;
    Bs[kc + 2][row] = bv0.z; Bs[kc + 3][row] = bv0.w;
    Bs[kc + 4][row] = bv1.x; Bs[kc + 5][row] = bv1.y;
    Bs[kc + 6][row] = bv1.z; Bs[kc + 7][row] = bv1.w;
    __syncthreads();
#pragma unroll 8
    for (int k = 0; k < 32; ++k) {
      float4 av = *(const float4*)&As[k][ty * 4];
      float4 bv = *(const float4*)&Bs[k][tx * 4];
      acc[0][0] += av.x * bv.x; acc[0][1] += av.x * bv.y;
      acc[0][2] += av.x * bv.z; acc[0][3] += av.x * bv.w;
      acc[1][0] += av.y * bv.x; acc[1][1] += av.y * bv.y;
      acc[1][2] += av.y * bv.z; acc[1][3] += av.y * bv.w;
      acc[2][0] += av.z * bv.x; acc[2][1] += av.z * bv.y;
      acc[2][2] += av.z * bv.z; acc[2][3] += av.z * bv.w;
      acc[3][0] += av.w * bv.x; acc[3][1] += av.w * bv.y;
      acc[3][2] += av.w * bv.z; acc[3][3] += av.w * bv.w;
    }
  }
  float bj[4];
#pragma unroll
  for (int j = 0; j < 4; ++j) {
    int n = n0 + tx * 4 + j;
    bj[j] = bias1[n] + bias2[n];
  }
#pragma unroll
  for (int i = 0; i < 4; ++i) {
    float4 cv = make_float4(acc[i][0] + bj[0], acc[i][1] + bj[1],
                            acc[i][2] + bj[2], acc[i][3] + bj[3]);
    *(float4*)&C[(size_t)(m0 + ty * 4 + i) * HH + n0 + tx * 4] = cv;
  }
}

__device__ __forceinline__ void fma2(float2& d, const float2 a, const float b) {
  d.x = __builtin_fmaf(a.x, b, d.x);
  d.y = __builtin_fmaf(a.y, b, d.y);
}

// Recurrence: per block 2 batches, 1024 threads.
// Thread (g = tid>>7, tt = tid&127): partial dot for outputs 4tt..4tt+3
// over j in [64g, 64g+64), both batches. WT[j][i] = W_hh[i][j].
// 2-chunk register double-buffer prefetch; weight addresses are
// step-invariant so chunks 14,15 prefetch next step's chunks 0,1 (values
// complete at the __syncthreads vmcnt drain -> step t+1 chunk 0 is wait-free).
template <bool WRITE_OUT>
__global__ __launch_bounds__(1024, 1) void rec_kernel(
    const float* __restrict__ xp,   // [B][S][H]
    const float* __restrict__ WT,   // [H][H] transposed
    float* __restrict__ outp,       // [B][S][H]  (layer 0)
    float* __restrict__ pooled) {   // [B][H]     (layer 1)
  const int tid = threadIdx.x;
  const int g = tid >> 7;
  const int tt = tid & 127;
  const int b0 = blockIdx.x * 2;
  __shared__ alignas(16) float hs[2][HH];
  __shared__ alignas(16) float part[8][2][HH];
  if (tid < HH) { hs[0][tid] = 0.f; hs[1][tid] = 0.f; }
  __syncthreads();

  const int bb = tid >> 9;       // finalize mapping: batch select
  const int oi = tid & 511;      // finalize output index
  float pacc = 0.f;
  const float* wp = WT + (size_t)(g * 64) * HH + tt * 4;

  // preload chunks 0,1
  float4 wb[2][4];
#pragma unroll
  for (int c = 0; c < 2; ++c) {
    const float* pp = wp + (size_t)c * 4 * HH;
    wb[c][0] = *(const float4*)pp;
    wb[c][1] = *(const float4*)(pp + HH);
    wb[c][2] = *(const float4*)(pp + 2 * HH);
    wb[c][3] = *(const float4*)(pp + 3 * HH);
  }

  const size_t xbase = (size_t)(b0 + bb) * (SS * HH) + oi;

  for (int t = 0; t < SS; ++t) {
    float xv = xp[xbase + (size_t)t * HH];   // issue early, used after barrier
    float2 a0lo = {0.f, 0.f}, a0hi = {0.f, 0.f};
    float2 a1lo = {0.f, 0.f}, a1hi = {0.f, 0.f};
#pragma unroll
    for (int jj = 0; jj < 16; ++jj) {
      const int cur = jj & 1;
      float4 w0 = wb[cur][0], w1 = wb[cur][1], w2 = wb[cur][2], w3 = wb[cur][3];
      // prefetch chunk (jj+2) mod 16 -- wraps into next step (same addresses)
      const int pj = (jj + 2) & 15;
      const float* pp = wp + (size_t)pj * 4 * HH;
      wb[cur][0] = *(const float4*)pp;
      wb[cur][1] = *(const float4*)(pp + HH);
      wb[cur][2] = *(const float4*)(pp + 2 * HH);
      wb[cur][3] = *(const float4*)(pp + 3 * HH);

      float4 h0 = *(const float4*)&hs[0][g * 64 + jj * 4];
      float4 h1 = *(const float4*)&hs[1][g * 64 + jj * 4];

      float2 w0l = {w0.x, w0.y}, w0h = {w0.z, w0.w};
      float2 w1l = {w1.x, w1.y}, w1h = {w1.z, w1.w};
      float2 w2l = {w2.x, w2.y}, w2h = {w2.z, w2.w};
      float2 w3l = {w3.x, w3.y}, w3h = {w3.z, w3.w};
      fma2(a0lo, w0l, h0.x); fma2(a0hi, w0h, h0.x);
      fma2(a1lo, w0l, h1.x); fma2(a1hi, w0h, h1.x);
      fma2(a0lo, w1l, h0.y); fma2(a0hi, w1h, h0.y);
      fma2(a1lo, w1l, h1.y); fma2(a1hi, w1h, h1.y);
      fma2(a0lo, w2l, h0.z); fma2(a0hi, w2h, h0.z);
      fma2(a1lo, w2l, h1.z); fma2(a1hi, w2h, h1.z);
      fma2(a0lo, w3l, h0.w); fma2(a0hi, w3h, h0.w);
      fma2(a1lo, w3l, h1.w); fma2(a1hi, w3h, h1.w);
    }
    *(float4*)&part[g][0][tt * 4] = make_float4(a0lo.x, a0lo.y, a0hi.x, a0hi.y);
    *(float4*)&part[g][1][tt * 4] = make_float4(a1lo.x, a1lo.y, a1hi.x, a1hi.y);
    __syncthreads();

    float v = xv;
#pragma unroll
    for (int gg = 0; gg < 8; ++gg) v += part[gg][bb][oi];
    float nh = tanhf(v);
    hs[bb][oi] = nh;   // all reads of old hs completed before the barrier
    if (WRITE_OUT)
      outp[xbase + (size_t)t * HH] = nh;
    else
      pacc += nh;
    __syncthreads();
  }
  if (!WRITE_OUT)
    pooled[(size_t)(b0 + bb) * HH + oi] = pacc * (1.0f / SS);
}

// Final head: out[b][c] = sum_k pooled[b][k] * W_out[c][k] + b_out[c]
__global__ void out_kernel(const float* __restrict__ pooled,
                           const float* __restrict__ W_out,
                           const float* __restrict__ b_out,
                           float* __restrict__ out) {
  int tid = threadIdx.x;
  if (tid >= BB * 2) return;
  int b = tid >> 1, c = tid & 1;
  float acc = b_out[c];
  for (int k = 0; k < HH; ++k)
    acc += pooled[(size_t)b * HH + k] * W_out[(size_t)c * HH + k];
  out[(size_t)b * 2 + c] = acc;
}

extern "C" void kernel_launch(void* const* d_in, const int* in_sizes, int n_in,
                              void* d_out, int out_size, void* d_ws, size_t ws_size,
                              hipStream_t stream) {
  const int*   x     = (const int*)d_in[0];
  const float* emb   = (const float*)d_in[1];
  const float* W_ih0 = (const float*)d_in[2];
  const float* W_hh0 = (const float*)d_in[3];
  const float* b_ih0 = (const float*)d_in[4];
  const float* b_hh0 = (const float*)d_in[5];
  const float* W_ih1 = (const float*)d_in[6];
  const float* W_hh1 = (const float*)d_in[7];
  const float* b_ih1 = (const float*)d_in[8];
  const float* b_hh1 = (const float*)d_in[9];
  const float* W_out = (const float*)d_in[10];
  const float* b_out = (const float*)d_in[11];

  float* ws = (float*)d_ws;
  const size_t NBSH = (size_t)BB * SS * HH;  // 16777216
  float* xp     = ws;                 // xp0, later xp1 (64 MB)
  float* out0   = ws + NBSH;          // layer-0 output (64 MB)
  float* WT0    = ws + 2 * NBSH;      // 1 MB
  float* WT1    = WT0 + HH * HH;      // 1 MB
  float* pooled = WT1 + HH * HH;      // 128 KB

  dim3 tb(32, 8), tg(16, 16);
  transpose512<<<tg, tb, 0, stream>>>(W_hh0, WT0);
  transpose512<<<tg, tb, 0, stream>>>(W_hh1, WT1);

  dim3 gg(512, 8);
  xp_gemm<EE, true><<<gg, 256, 0, stream>>>(nullptr, x, emb, W_ih0, b_ih0, b_hh0, xp);
  rec_kernel<true><<<32, 1024, 0, stream>>>(xp, WT0, out0, nullptr);
  xp_gemm<HH, false><<<gg, 256, 0, stream>>>(out0, nullptr, nullptr, W_ih1, b_ih1, b_hh1, xp);
  rec_kernel<false><<<32, 1024, 0, stream>>>(xp, WT1, nullptr, pooled);
  out_kernel<<<1, 128, 0, stream>>>(pooled, W_out, b_out, (float*)d_out);
}

// Round 4
// 28310.403 us; speedup vs baseline: 1.7211x; 1.7211x over previous
//
#include <hip/hip_runtime.h>
#include <math.h>

// Problem constants
#define BB 64      // batch
#define SS 512     // seq
#define EE 256     // embed
#define HH 512     // hidden

// Recurrence decomposition: 16 groups x 4 batches; each group = 8 blocks;
// block handles 64 outputs x 4 batches, W-slice (64x512 f32 = 128KB) lives
// in REGISTERS (64 f32/thread x 512 threads) for all 512 steps. Blocks of a
// group exchange h each step via L2 (double-buffered slots + monotonic
// agent-scope counters). This removes the 1MB/step/CU weight stream that
// capped rounds 1-3 at ~7.3us/step (per-CU L2 path ~60B/cyc).
#define NGROUPS 16
#define GSLICES 8          // blocks per group
#define BPG 4              // batches per group
#define RECT 512           // threads per rec block

// ---------------------------------------------------------------------------

// W transpose: WT[j][i] = W[i][j], 512x512
__global__ void transpose512(const float* __restrict__ in, float* __restrict__ out) {
  __shared__ float tile[32][33];
  int bx = blockIdx.x * 32, by = blockIdx.y * 32;
  int x = threadIdx.x, y0 = threadIdx.y;  // block (32,8)
  for (int dy = 0; dy < 32; dy += 8)
    tile[y0 + dy][x] = in[(size_t)(by + y0 + dy) * HH + bx + x];
  __syncthreads();
  for (int dy = 0; dy < 32; dy += 8)
    out[(size_t)(bx + y0 + dy) * HH + by + x] = tile[x][y0 + dy];
}

// Tiled GEMM: C[m][n] = sum_k A[m][k] * Wn[n][k] + bias1[n] + bias2[n]
template <int K, bool GATHER>
__global__ __launch_bounds__(256) void xp_gemm(
    const float* __restrict__ Asrc, const int* __restrict__ xidx,
    const float* __restrict__ emb, const float* __restrict__ Wn,
    const float* __restrict__ bias1, const float* __restrict__ bias2,
    float* __restrict__ C) {
  const int tid = threadIdx.x;
  const int m0 = blockIdx.x * 64;
  const int n0 = blockIdx.y * 64;
  __shared__ alignas(16) float As[32][68];
  __shared__ alignas(16) float Bs[32][68];
  __shared__ int xs[64];
  if (GATHER) {
    if (tid < 64) xs[tid] = xidx[m0 + tid];
    __syncthreads();
  }
  float acc[4][4] = {};
  const int ty = tid >> 4, tx = tid & 15;
  const int row = tid >> 2;          // 0..63
  const int kc = (tid & 3) * 8;      // 0,8,16,24

  for (int k0 = 0; k0 < K; k0 += 32) {
    const float* ap;
    if (GATHER) ap = emb + (size_t)xs[row] * EE + (k0 + kc);
    else        ap = Asrc + (size_t)(m0 + row) * K + (k0 + kc);
    float4 av0 = *(const float4*)ap;
    float4 av1 = *(const float4*)(ap + 4);
    const float* bp = Wn + (size_t)(n0 + row) * K + (k0 + kc);
    float4 bv0 = *(const float4*)bp;
    float4 bv1 = *(const float4*)(bp + 4);
    __syncthreads();
    As[kc + 0][row] = av0.x; As[kc + 1][row] = av0.y;
    As[kc + 2][row] = av0.z; As[kc + 3][row] = av0.w;
    As[kc + 4][row] = av1.x; As[kc + 5][row] = av1.y;
    As[kc + 6][row] = av1.z; As[kc + 7][row] = av1.w;
    Bs[kc + 0][row] = bv0.x; Bs[kc + 1][row] = bv0.y;
    Bs[kc + 2][row] = bv0.z; Bs[kc + 3][row] = bv0.w;
    Bs[kc + 4][row] = bv1.x; Bs[kc + 5][row] = bv1.y;
    Bs[kc + 6][row] = bv1.z; Bs[kc + 7][row] = bv1.w;
    __syncthreads();
#pragma unroll 8
    for (int k = 0; k < 32; ++k) {
      float4 av = *(const float4*)&As[k][ty * 4];
      float4 bv = *(const float4*)&Bs[k][tx * 4];
      acc[0][0] += av.x * bv.x; acc[0][1] += av.x * bv.y;
      acc[0][2] += av.x * bv.z; acc[0][3] += av.x * bv.w;
      acc[1][0] += av.y * bv.x; acc[1][1] += av.y * bv.y;
      acc[1][2] += av.y * bv.z; acc[1][3] += av.y * bv.w;
      acc[2][0] += av.z * bv.x; acc[2][1] += av.z * bv.y;
      acc[2][2] += av.z * bv.z; acc[2][3] += av.z * bv.w;
      acc[3][0] += av.w * bv.x; acc[3][1] += av.w * bv.y;
      acc[3][2] += av.w * bv.z; acc[3][3] += av.w * bv.w;
    }
  }
  float bj[4];
#pragma unroll
  for (int j = 0; j < 4; ++j) {
    int n = n0 + tx * 4 + j;
    bj[j] = bias1[n] + bias2[n];
  }
#pragma unroll
  for (int i = 0; i < 4; ++i) {
    float4 cv = make_float4(acc[i][0] + bj[0], acc[i][1] + bj[1],
                            acc[i][2] + bj[2], acc[i][3] + bj[3]);
    *(float4*)&C[(size_t)(m0 + ty * 4 + i) * HH + n0 + tx * 4] = cv;
  }
}

// zero the h-exchange buffers + counters (must run every launch: graph
// replays do not re-poison the workspace and counters are monotonic)
__global__ void init_sync(float* __restrict__ hbuf, unsigned* __restrict__ cnt) {
  int i = blockIdx.x * 256 + threadIdx.x;
  if (i < 2 * NGROUPS * 2 * BPG * HH) hbuf[i] = 0.f;
  if (i < 2 * NGROUPS * 2) cnt[i] = 0u;
}

__device__ __forceinline__ void fma4(float4& d, const float4 w, const float s) {
  d.x = __builtin_fmaf(w.x, s, d.x);
  d.y = __builtin_fmaf(w.y, s, d.y);
  d.z = __builtin_fmaf(w.z, s, d.z);
  d.w = __builtin_fmaf(w.w, s, d.w);
}

// Distributed recurrence.
// bid -> r = bid&7 (XCD-guess), k = bid>>3; group = (r<<1)|(k>>3), slice = k&7.
// Thread (oo4 = tid&15, jg = tid>>4): outputs obase..obase+3 (obase =
// slice*64 + oo4*4), j-range [jg*16, jg*16+16), all 4 batches.
// wreg[j] = WT[jg*16+j][obase..obase+3] -- registers, loaded once.
template <bool WRITE_OUT>
__global__ __launch_bounds__(RECT, 2) void rec_sync(
    const float* __restrict__ xp,     // [BB][SS][HH]
    const float* __restrict__ WT,     // [HH][HH] = W_hh^T
    float* __restrict__ outp,         // [BB][SS][HH] (layer 0)
    float* __restrict__ pooled,       // [BB][HH]     (layer 1)
    float* __restrict__ hbuf,         // [NGROUPS][2][BPG][HH]
    unsigned* __restrict__ cnt) {     // [NGROUPS][2]
  const int tid = threadIdx.x;
  const int bid = blockIdx.x;
  const int r = bid & 7, k = bid >> 3;
  const int slice = k & 7;
  const int grp = (r << 1) | (k >> 3);
  const int oo4 = tid & 15;
  const int jg = tid >> 4;
  const int obase = slice * 64 + oo4 * 4;

  // ---- load W slice into registers (once) ----
  float4 wreg[16];
#pragma unroll
  for (int j = 0; j < 16; ++j)
    wreg[j] = *(const float4*)&WT[(size_t)(jg * 16 + j) * HH + obase];

  float* hb = hbuf + (size_t)grp * (2 * BPG * HH);
  unsigned* cp = cnt + grp * 2;

  __shared__ float part[8][16][17];   // [wave][oo4][b*4+c], padded

  const int wave = tid >> 6, wl = tid & 63;
  const int fo = tid & 63, fbb = tid >> 6;          // finalize map (tid<256)
  const int fog = slice * 64 + fo;                   // finalize global output
  const size_t fxbase = (size_t)(grp * BPG + fbb) * (SS * HH) + fog;
  float pacc = 0.f;

  for (int t = 0; t < SS; ++t) {
    const int wp = t & 1, rp = wp ^ 1;
    // xp prefetch (waves 0..3 only; wave-uniform branch)
    float xv = 0.f;
    if (tid < 256) xv = xp[fxbase + (size_t)t * HH];

    // ---- read h_{t-1} (slot rp): 16-lane-broadcast global loads ----
    float4 hreg[4][4];
#pragma unroll
    for (int b = 0; b < 4; ++b)
#pragma unroll
      for (int q = 0; q < 4; ++q)
        hreg[b][q] = *(const float4*)&hb[((size_t)rp * BPG + b) * HH + jg * 16 + q * 4];

    // ---- 256 FMAs, all operands in registers ----
    float4 acc[4] = {{0,0,0,0},{0,0,0,0},{0,0,0,0},{0,0,0,0}};
#pragma unroll
    for (int q = 0; q < 4; ++q) {
      float4 w0 = wreg[q * 4 + 0], w1 = wreg[q * 4 + 1];
      float4 w2 = wreg[q * 4 + 2], w3 = wreg[q * 4 + 3];
#pragma unroll
      for (int b = 0; b < 4; ++b) {
        float4 hv = hreg[b][q];
        fma4(acc[b], w0, hv.x);
        fma4(acc[b], w1, hv.y);
        fma4(acc[b], w2, hv.z);
        fma4(acc[b], w3, hv.w);
      }
    }

    // ---- reduce over jg: 4 j-groups within wave via shfl ----
#pragma unroll
    for (int b = 0; b < 4; ++b) {
      acc[b].x += __shfl_down(acc[b].x, 32); acc[b].y += __shfl_down(acc[b].y, 32);
      acc[b].z += __shfl_down(acc[b].z, 32); acc[b].w += __shfl_down(acc[b].w, 32);
      acc[b].x += __shfl_down(acc[b].x, 16); acc[b].y += __shfl_down(acc[b].y, 16);
      acc[b].z += __shfl_down(acc[b].z, 16); acc[b].w += __shfl_down(acc[b].w, 16);
    }
    if (wl < 16) {
#pragma unroll
      for (int b = 0; b < 4; ++b) {
        part[wave][wl][b * 4 + 0] = acc[b].x;
        part[wave][wl][b * 4 + 1] = acc[b].y;
        part[wave][wl][b * 4 + 2] = acc[b].z;
        part[wave][wl][b * 4 + 3] = acc[b].w;
      }
    }
    __syncthreads();

    // ---- finalize: 8-wave reduce + tanh + publish h slice ----
    if (tid < 256) {
      float v = xv;
#pragma unroll
      for (int w = 0; w < 8; ++w) v += part[w][fo >> 2][fbb * 4 + (fo & 3)];
      float h = tanhf(v);
      hb[((size_t)wp * BPG + fbb) * HH + fog] = h;
      if (WRITE_OUT) outp[fxbase + (size_t)t * HH] = h;
      else pacc += h;
    }
    __syncthreads();   // drains vmcnt: h stores complete before the release

    // ---- group barrier: monotonic counter, agent scope ----
    if (tid == 0)
      __hip_atomic_fetch_add(&cp[wp], 1u, __ATOMIC_RELEASE, __HIP_MEMORY_SCOPE_AGENT);
    const unsigned target = (unsigned)GSLICES * (unsigned)((t >> 1) + 1);
    while (__hip_atomic_load(&cp[wp], __ATOMIC_ACQUIRE, __HIP_MEMORY_SCOPE_AGENT) < target)
      __builtin_amdgcn_s_sleep(2);
  }

  if (!WRITE_OUT && tid < 256)
    pooled[(size_t)(grp * BPG + fbb) * HH + fog] = pacc * (1.0f / SS);
}

// Final head: out[b][c] = sum_k pooled[b][k] * W_out[c][k] + b_out[c]
__global__ void out_kernel(const float* __restrict__ pooled,
                           const float* __restrict__ W_out,
                           const float* __restrict__ b_out,
                           float* __restrict__ out) {
  int tid = threadIdx.x;
  if (tid >= BB * 2) return;
  int b = tid >> 1, c = tid & 1;
  float acc = b_out[c];
  for (int k = 0; k < HH; ++k)
    acc += pooled[(size_t)b * HH + k] * W_out[(size_t)c * HH + k];
  out[(size_t)b * 2 + c] = acc;
}

extern "C" void kernel_launch(void* const* d_in, const int* in_sizes, int n_in,
                              void* d_out, int out_size, void* d_ws, size_t ws_size,
                              hipStream_t stream) {
  const int*   x     = (const int*)d_in[0];
  const float* emb   = (const float*)d_in[1];
  const float* W_ih0 = (const float*)d_in[2];
  const float* W_hh0 = (const float*)d_in[3];
  const float* b_ih0 = (const float*)d_in[4];
  const float* b_hh0 = (const float*)d_in[5];
  const float* W_ih1 = (const float*)d_in[6];
  const float* W_hh1 = (const float*)d_in[7];
  const float* b_ih1 = (const float*)d_in[8];
  const float* b_hh1 = (const float*)d_in[9];
  const float* W_out = (const float*)d_in[10];
  const float* b_out = (const float*)d_in[11];

  float* ws = (float*)d_ws;
  const size_t NBSH = (size_t)BB * SS * HH;  // 16777216
  float* xp     = ws;                  // 64 MB (xp0, later xp1)
  float* out0   = ws + NBSH;           // 64 MB
  float* WT0    = ws + 2 * NBSH;       // 1 MB
  float* WT1    = WT0 + HH * HH;       // 1 MB
  float* pooled = WT1 + HH * HH;       // 128 KB
  float* hbuf0  = pooled + BB * HH;    // 256 KB  [16][2][4][512]
  float* hbuf1  = hbuf0 + NGROUPS * 2 * BPG * HH;  // 256 KB
  unsigned* cnt0 = (unsigned*)(hbuf1 + NGROUPS * 2 * BPG * HH);  // 32 u32
  // cnt1 = cnt0 + 32 (contiguous; init_sync zeroes both)

  init_sync<<<512, 256, 0, stream>>>(hbuf0, cnt0);

  dim3 tb(32, 8), tg(16, 16);
  transpose512<<<tg, tb, 0, stream>>>(W_hh0, WT0);
  transpose512<<<tg, tb, 0, stream>>>(W_hh1, WT1);

  dim3 gg(512, 8);
  xp_gemm<EE, true><<<gg, 256, 0, stream>>>(nullptr, x, emb, W_ih0, b_ih0, b_hh0, xp);
  rec_sync<true><<<NGROUPS * GSLICES, RECT, 0, stream>>>(
      xp, WT0, out0, nullptr, hbuf0, cnt0);
  xp_gemm<HH, false><<<gg, 256, 0, stream>>>(out0, nullptr, nullptr, W_ih1, b_ih1, b_hh1, xp);
  rec_sync<false><<<NGROUPS * GSLICES, RECT, 0, stream>>>(
      xp, WT1, nullptr, pooled, hbuf1, cnt0 + NGROUPS * 2);
  out_kernel<<<1, 128, 0, stream>>>(pooled, W_out, b_out, (float*)d_out);
}

// Round 5
// 6053.606 us; speedup vs baseline: 8.0491x; 4.6766x over previous
//
#include <hip/hip_runtime.h>
#include <math.h>

// Problem constants
#define BB 64      // batch
#define SS 512     // seq
#define EE 256     // embed
#define HH 512     // hidden

// Recurrence decomposition: 16 groups x 4 batches; each group = 8 blocks;
// block handles 64 outputs x 4 batches, W-slice (64x512 f32 = 128KB) lives
// in REGISTERS (64 f32/thread x 512 threads) for all 512 steps. Blocks of a
// group exchange h each step via L2 (double-buffered slots + monotonic
// agent-scope counters).
//
// Round-5 fixes (round 4 ran at 27us/step):
//  (a) wreg was demoted (VGPR_Count=60): allocator remat'd the loop-invariant
//      WT loads back into the loop. Fix: empty-asm pin => remat illegal.
//  (b) all 512 threads spun on agent-scope acquire loads (each poll = vmcnt
//      drain + CU-wide L1 invalidate, 8 waves/block polling every ~130cyc).
//      Fix: single-poller barrier (tid 0 add+spin, rest wait at s_barrier).
#define NGROUPS 16
#define GSLICES 8          // blocks per group
#define BPG 4              // batches per group
#define RECT 512           // threads per rec block

// ---------------------------------------------------------------------------

// W transpose: WT[j][i] = W[i][j], 512x512
__global__ void transpose512(const float* __restrict__ in, float* __restrict__ out) {
  __shared__ float tile[32][33];
  int bx = blockIdx.x * 32, by = blockIdx.y * 32;
  int x = threadIdx.x, y0 = threadIdx.y;  // block (32,8)
  for (int dy = 0; dy < 32; dy += 8)
    tile[y0 + dy][x] = in[(size_t)(by + y0 + dy) * HH + bx + x];
  __syncthreads();
  for (int dy = 0; dy < 32; dy += 8)
    out[(size_t)(bx + y0 + dy) * HH + by + x] = tile[x][y0 + dy];
}

// Tiled GEMM: C[m][n] = sum_k A[m][k] * Wn[n][k] + bias1[n] + bias2[n]
template <int K, bool GATHER>
__global__ __launch_bounds__(256) void xp_gemm(
    const float* __restrict__ Asrc, const int* __restrict__ xidx,
    const float* __restrict__ emb, const float* __restrict__ Wn,
    const float* __restrict__ bias1, const float* __restrict__ bias2,
    float* __restrict__ C) {
  const int tid = threadIdx.x;
  const int m0 = blockIdx.x * 64;
  const int n0 = blockIdx.y * 64;
  __shared__ alignas(16) float As[32][68];
  __shared__ alignas(16) float Bs[32][68];
  __shared__ int xs[64];
  if (GATHER) {
    if (tid < 64) xs[tid] = xidx[m0 + tid];
    __syncthreads();
  }
  float acc[4][4] = {};
  const int ty = tid >> 4, tx = tid & 15;
  const int row = tid >> 2;          // 0..63
  const int kc = (tid & 3) * 8;      // 0,8,16,24

  for (int k0 = 0; k0 < K; k0 += 32) {
    const float* ap;
    if (GATHER) ap = emb + (size_t)xs[row] * EE + (k0 + kc);
    else        ap = Asrc + (size_t)(m0 + row) * K + (k0 + kc);
    float4 av0 = *(const float4*)ap;
    float4 av1 = *(const float4*)(ap + 4);
    const float* bp = Wn + (size_t)(n0 + row) * K + (k0 + kc);
    float4 bv0 = *(const float4*)bp;
    float4 bv1 = *(const float4*)(bp + 4);
    __syncthreads();
    As[kc + 0][row] = av0.x; As[kc + 1][row] = av0.y;
    As[kc + 2][row] = av0.z; As[kc + 3][row] = av0.w;
    As[kc + 4][row] = av1.x; As[kc + 5][row] = av1.y;
    As[kc + 6][row] = av1.z; As[kc + 7][row] = av1.w;
    Bs[kc + 0][row] = bv0.x; Bs[kc + 1][row] = bv0.y;
    Bs[kc + 2][row] = bv0.z; Bs[kc + 3][row] = bv0.w;
    Bs[kc + 4][row] = bv1.x; Bs[kc + 5][row] = bv1.y;
    Bs[kc + 6][row] = bv1.z; Bs[kc + 7][row] = bv1.w;
    __syncthreads();
#pragma unroll 8
    for (int k = 0; k < 32; ++k) {
      float4 av = *(const float4*)&As[k][ty * 4];
      float4 bv = *(const float4*)&Bs[k][tx * 4];
      acc[0][0] += av.x * bv.x; acc[0][1] += av.x * bv.y;
      acc[0][2] += av.x * bv.z; acc[0][3] += av.x * bv.w;
      acc[1][0] += av.y * bv.x; acc[1][1] += av.y * bv.y;
      acc[1][2] += av.y * bv.z; acc[1][3] += av.y * bv.w;
      acc[2][0] += av.z * bv.x; acc[2][1] += av.z * bv.y;
      acc[2][2] += av.z * bv.z; acc[2][3] += av.z * bv.w;
      acc[3][0] += av.w * bv.x; acc[3][1] += av.w * bv.y;
      acc[3][2] += av.w * bv.z; acc[3][3] += av.w * bv.w;
    }
  }
  float bj[4];
#pragma unroll
  for (int j = 0; j < 4; ++j) {
    int n = n0 + tx * 4 + j;
    bj[j] = bias1[n] + bias2[n];
  }
#pragma unroll
  for (int i = 0; i < 4; ++i) {
    float4 cv = make_float4(acc[i][0] + bj[0], acc[i][1] + bj[1],
                            acc[i][2] + bj[2], acc[i][3] + bj[3]);
    *(float4*)&C[(size_t)(m0 + ty * 4 + i) * HH + n0 + tx * 4] = cv;
  }
}

// zero the h-exchange buffers + counters (must run every launch: graph
// replays do not re-poison the workspace and counters are monotonic)
__global__ void init_sync(float* __restrict__ hbuf, unsigned* __restrict__ cnt) {
  int i = blockIdx.x * 256 + threadIdx.x;
  if (i < 2 * NGROUPS * 2 * BPG * HH) hbuf[i] = 0.f;
  if (i < 2 * NGROUPS * 2) cnt[i] = 0u;
}

__device__ __forceinline__ void fma4(float4& d, const float4 w, const float s) {
  d.x = __builtin_fmaf(w.x, s, d.x);
  d.y = __builtin_fmaf(w.y, s, d.y);
  d.z = __builtin_fmaf(w.z, s, d.z);
  d.w = __builtin_fmaf(w.w, s, d.w);
}

// Distributed recurrence.
// bid -> r = bid&7 (XCD-guess), k = bid>>3; group = (r<<1)|(k>>3), slice = k&7.
// Thread (oo4 = tid&15, jg = tid>>4): outputs obase..obase+3 (obase =
// slice*64 + oo4*4), j-range [jg*16, jg*16+16), all 4 batches.
// wreg[j] = WT[jg*16+j][obase..obase+3] -- registers, loaded once, asm-pinned.
template <bool WRITE_OUT>
__global__ __launch_bounds__(RECT, 2) void rec_sync(
    const float* __restrict__ xp,     // [BB][SS][HH]
    const float* __restrict__ WT,     // [HH][HH] = W_hh^T
    float* __restrict__ outp,         // [BB][SS][HH] (layer 0)
    float* __restrict__ pooled,       // [BB][HH]     (layer 1)
    float* __restrict__ hbuf,         // [NGROUPS][2][BPG][HH]
    unsigned* __restrict__ cnt) {     // [NGROUPS][2]
  const int tid = threadIdx.x;
  const int bid = blockIdx.x;
  const int r = bid & 7, k = bid >> 3;
  const int slice = k & 7;
  const int grp = (r << 1) | (k >> 3);
  const int oo4 = tid & 15;
  const int jg = tid >> 4;
  const int obase = slice * 64 + oo4 * 4;

  // ---- load W slice into registers (once); pin so the allocator cannot
  //      remat the loads back into the loop (round-4 failure mode) ----
  float4 wreg[16];
#pragma unroll
  for (int j = 0; j < 16; ++j)
    wreg[j] = *(const float4*)&WT[(size_t)(jg * 16 + j) * HH + obase];
#pragma unroll
  for (int j = 0; j < 16; ++j)
    asm volatile("" : "+v"(wreg[j].x), "+v"(wreg[j].y),
                      "+v"(wreg[j].z), "+v"(wreg[j].w));

  float* hb = hbuf + (size_t)grp * (2 * BPG * HH);
  unsigned* cp = cnt + grp * 2;

  __shared__ float part[8][16][17];   // [wave][oo4][b*4+c], padded

  const int wave = tid >> 6, wl = tid & 63;
  const int fo = tid & 63, fbb = tid >> 6;          // finalize map (tid<256)
  const int fog = slice * 64 + fo;                   // finalize global output
  const size_t fxbase = (size_t)(grp * BPG + fbb) * (SS * HH) + fog;
  float pacc = 0.f;

  for (int t = 0; t < SS; ++t) {
    const int wp = t & 1, rp = wp ^ 1;
    // xp prefetch (waves 0..3 only; wave-uniform branch)
    float xv = 0.f;
    if (tid < 256) xv = xp[fxbase + (size_t)t * HH];

    // ---- read h_{t-1} (slot rp): 16-lane-broadcast global loads ----
    float4 hreg[4][4];
#pragma unroll
    for (int b = 0; b < 4; ++b)
#pragma unroll
      for (int q = 0; q < 4; ++q)
        hreg[b][q] = *(const float4*)&hb[((size_t)rp * BPG + b) * HH + jg * 16 + q * 4];

    // ---- 256 FMAs, all operands in registers ----
    float4 acc[4] = {{0,0,0,0},{0,0,0,0},{0,0,0,0},{0,0,0,0}};
#pragma unroll
    for (int q = 0; q < 4; ++q) {
      float4 w0 = wreg[q * 4 + 0], w1 = wreg[q * 4 + 1];
      float4 w2 = wreg[q * 4 + 2], w3 = wreg[q * 4 + 3];
#pragma unroll
      for (int b = 0; b < 4; ++b) {
        float4 hv = hreg[b][q];
        fma4(acc[b], w0, hv.x);
        fma4(acc[b], w1, hv.y);
        fma4(acc[b], w2, hv.z);
        fma4(acc[b], w3, hv.w);
      }
    }

    // ---- reduce over jg: 4 j-groups within wave via shfl ----
#pragma unroll
    for (int b = 0; b < 4; ++b) {
      acc[b].x += __shfl_down(acc[b].x, 32); acc[b].y += __shfl_down(acc[b].y, 32);
      acc[b].z += __shfl_down(acc[b].z, 32); acc[b].w += __shfl_down(acc[b].w, 32);
      acc[b].x += __shfl_down(acc[b].x, 16); acc[b].y += __shfl_down(acc[b].y, 16);
      acc[b].z += __shfl_down(acc[b].z, 16); acc[b].w += __shfl_down(acc[b].w, 16);
    }
    if (wl < 16) {
#pragma unroll
      for (int b = 0; b < 4; ++b) {
        part[wave][wl][b * 4 + 0] = acc[b].x;
        part[wave][wl][b * 4 + 1] = acc[b].y;
        part[wave][wl][b * 4 + 2] = acc[b].z;
        part[wave][wl][b * 4 + 3] = acc[b].w;
      }
    }
    __syncthreads();

    // ---- finalize: 8-wave reduce + tanh + publish h slice ----
    if (tid < 256) {
      float v = xv;
#pragma unroll
      for (int w = 0; w < 8; ++w) v += part[w][fo >> 2][fbb * 4 + (fo & 3)];
      float h = tanhf(v);
      hb[((size_t)wp * BPG + fbb) * HH + fog] = h;
      if (WRITE_OUT) outp[fxbase + (size_t)t * HH] = h;
      else pacc += h;
    }
    __syncthreads();   // all waves drain vmcnt: h stores visible in L2

    // ---- group barrier: SINGLE poller (tid 0), monotonic counter ----
    if (tid == 0) {
      __hip_atomic_fetch_add(&cp[wp], 1u, __ATOMIC_RELEASE, __HIP_MEMORY_SCOPE_AGENT);
      const unsigned target = (unsigned)GSLICES * (unsigned)((t >> 1) + 1);
      while (__hip_atomic_load(&cp[wp], __ATOMIC_ACQUIRE, __HIP_MEMORY_SCOPE_AGENT) < target)
        __builtin_amdgcn_s_sleep(1);
    }
    __syncthreads();   // release other waves; acquire's L1-inv already done (CU-wide)
  }

  if (!WRITE_OUT && tid < 256)
    pooled[(size_t)(grp * BPG + fbb) * HH + fog] = pacc * (1.0f / SS);
}

// Final head: out[b][c] = sum_k pooled[b][k] * W_out[c][k] + b_out[c]
__global__ void out_kernel(const float* __restrict__ pooled,
                           const float* __restrict__ W_out,
                           const float* __restrict__ b_out,
                           float* __restrict__ out) {
  int tid = threadIdx.x;
  if (tid >= BB * 2) return;
  int b = tid >> 1, c = tid & 1;
  float acc = b_out[c];
  for (int k = 0; k < HH; ++k)
    acc += pooled[(size_t)b * HH + k] * W_out[(size_t)c * HH + k];
  out[(size_t)b * 2 + c] = acc;
}

extern "C" void kernel_launch(void* const* d_in, const int* in_sizes, int n_in,
                              void* d_out, int out_size, void* d_ws, size_t ws_size,
                              hipStream_t stream) {
  const int*   x     = (const int*)d_in[0];
  const float* emb   = (const float*)d_in[1];
  const float* W_ih0 = (const float*)d_in[2];
  const float* W_hh0 = (const float*)d_in[3];
  const float* b_ih0 = (const float*)d_in[4];
  const float* b_hh0 = (const float*)d_in[5];
  const float* W_ih1 = (const float*)d_in[6];
  const float* W_hh1 = (const float*)d_in[7];
  const float* b_ih1 = (const float*)d_in[8];
  const float* b_hh1 = (const float*)d_in[9];
  const float* W_out = (const float*)d_in[10];
  const float* b_out = (const float*)d_in[11];

  float* ws = (float*)d_ws;
  const size_t NBSH = (size_t)BB * SS * HH;  // 16777216
  float* xp     = ws;                  // 64 MB (xp0, later xp1)
  float* out0   = ws + NBSH;           // 64 MB
  float* WT0    = ws + 2 * NBSH;       // 1 MB
  float* WT1    = WT0 + HH * HH;       // 1 MB
  float* pooled = WT1 + HH * HH;       // 128 KB
  float* hbuf0  = pooled + BB * HH;    // 256 KB  [16][2][4][512]
  float* hbuf1  = hbuf0 + NGROUPS * 2 * BPG * HH;  // 256 KB
  unsigned* cnt0 = (unsigned*)(hbuf1 + NGROUPS * 2 * BPG * HH);  // 64 u32
  // cnt1 = cnt0 + 32 (contiguous; init_sync zeroes both)

  init_sync<<<512, 256, 0, stream>>>(hbuf0, cnt0);

  dim3 tb(32, 8), tg(16, 16);
  transpose512<<<tg, tb, 0, stream>>>(W_hh0, WT0);
  transpose512<<<tg, tb, 0, stream>>>(W_hh1, WT1);

  dim3 gg(512, 8);
  xp_gemm<EE, true><<<gg, 256, 0, stream>>>(nullptr, x, emb, W_ih0, b_ih0, b_hh0, xp);
  rec_sync<true><<<NGROUPS * GSLICES, RECT, 0, stream>>>(
      xp, WT0, out0, nullptr, hbuf0, cnt0);
  xp_gemm<HH, false><<<gg, 256, 0, stream>>>(out0, nullptr, nullptr, W_ih1, b_ih1, b_hh1, xp);
  rec_sync<false><<<NGROUPS * GSLICES, RECT, 0, stream>>>(
      xp, WT1, nullptr, pooled, hbuf1, cnt0 + NGROUPS * 2);
  out_kernel<<<1, 128, 0, stream>>>(pooled, W_out, b_out, (float*)d_out);
}